// Round 9
// baseline (58.755 us; speedup 1.0000x reference)
//
#include <hip/hip_runtime.h>

#define THREADS 256
#define PB 12                        // puzzles per block (no loop)
#define CELLS_PB (PB * 81)           // 972 cells
#define WORKERS 243                  // phase-A lanes; 4 consecutive cells each
#define TOTW (CELLS_PB * 9)          // 8748 words staged
#define NF4 (TOTW / 4)               // 2187 float4 per block

typedef float f4 __attribute__((ext_vector_type(4)));
typedef __fp16 h2 __attribute__((ext_vector_type(2)));
typedef unsigned int u32;
typedef int i4 __attribute__((ext_vector_type(4)));

static __device__ __forceinline__ u32 pkrtz(float a, float b) {
  h2 v = __builtin_amdgcn_cvt_pkrtz(a, b);     // v_cvt_pkrtz_f16_f32
  return __builtin_bit_cast(u32, v);
}

// async global->LDS, 16B per lane; dest must be linear in lane (it is: slot r*256+tid)
static __device__ __forceinline__ void gload_lds16(const f4* g, f4* l) {
  __builtin_amdgcn_global_load_lds(
      (const __attribute__((address_space(1))) void*)g,
      (__attribute__((address_space(3))) void*)l, 16, 0, 0);
}

__global__ __launch_bounds__(THREADS) void sudoku_main(
    const float* __restrict__ logits,
    const int*   __restrict__ targets,
    const int*   __restrict__ puzzles,
    float* __restrict__ partial,      // transposed [5][ngrid]
    int B, int ngrid)
{
  __shared__ float buf[TOTW];         // staged logits f32 -> probs f16x2 in place (35 KB)
  __shared__ float sred[4][5];

  const int tid = threadIdx.x;
  const int g   = blockIdx.x;
  const long totalCells = (long)B * 81;
  const size_t lim4 = (size_t)(totalCells * 9 / 4);

  float a_focal=0.f, a_ent=0.f, a_msk=0.f, a_uniq=0.f, a_sq=0.f;

  // ---- stage logits ----
  const size_t gbase4 = (size_t)g * NF4;
  const bool full = (gbase4 + NF4) <= lim4;            // block-uniform
  if (full) {
    const f4* src = (const f4*)logits + gbase4;
    f4* dst = (f4*)buf;
    // 8 full-wave DMA rounds: 256 lanes x 16B, all lanes active, linear dest
#pragma unroll
    for (int r = 0; r < 8; ++r)
      gload_lds16(src + r * 256 + tid, dst + r * 256 + tid);
    // tail 139 f4 via regs
    if (tid < NF4 - 2048) dst[2048 + tid] = src[2048 + tid];
  } else {
    // last (partial) block: bounds-checked reg staging
    const f4* src = (const f4*)logits;
    f4* dst = (f4*)buf;
    if (tid < WORKERS) {
#pragma unroll
      for (int r = 0; r < 9; ++r) {
        size_t idx = gbase4 + r * WORKERS + tid;
        if (idx < lim4) dst[r * WORKERS + tid] = src[idx];
      }
    }
  }

  // ---- per-lane int loads: 4 cells as one int4 each (dense lines) ----
  const long cell0 = (long)g * CELLS_PB + 4 * tid;
  const bool vA = (tid < WORKERS) && (cell0 < totalCells);
  i4 tg4{}, pz4{};
  if (vA) {
    tg4 = *(const i4*)(targets + cell0);
    pz4 = *(const i4*)(puzzles + cell0);
  }
  __syncthreads();   // compiler emits s_waitcnt vmcnt(0) lgkmcnt(0) before s_barrier

  // ---- phase A: read own 144B slice (9x b128), 4 cells in regs ----
  if (vA) {
    f4 s[9];
#pragma unroll
    for (int q = 0; q < 9; ++q) s[q] = ((const f4*)buf)[tid * 9 + q];

#pragma unroll
    for (int k = 0; k < 4; ++k) {
      float l[9];
#pragma unroll
      for (int i = 0; i < 9; ++i) { const int w = 9 * k + i; l[i] = s[w >> 2][w & 3]; }
      int tg = tg4[k] - 1; tg = tg < 0 ? 0 : (tg > 8 ? 8 : tg);

      float t1 = l[0], t2 = -3.0e38f;            // branchless top-2 of logits
#pragma unroll
      for (int i = 1; i < 9; ++i) {
        float hi = fmaxf(t1, l[i]);
        float lo = fminf(t1, l[i]);
        t1 = hi; t2 = fmaxf(t2, lo);
      }
      float e[9], ssum = 0.f, lsum = 0.f, ltg = l[0];
#pragma unroll
      for (int i = 0; i < 9; ++i) {
        float x  = l[i] - t1;
        float ei = __expf(x);
        e[i] = ei; ssum += ei;
        lsum = fmaf(ei, x, lsum);
        if (i > 0) ltg = (tg == i) ? l[i] : ltg;
      }
      float inv_s = __builtin_amdgcn_rcpf(ssum);
      float logs  = __logf(ssum);
      float lpt   = (ltg - t1) - logs;
      float pt    = __expf(lpt);
      float om    = 1.f - pt;
      float focal = om * om * (-lpt);
      float ent   = logs - lsum * inv_s;
      float gap   = (1.f - __expf(t2 - t1)) * inv_s;
      float uq    = fmaxf(0.f, 1.f - gap);
      float mk    = (pz4[k] == 0) ? 1.f : 0.f;
      a_focal += focal * mk;
      a_ent   += ent * mk;
      a_msk   += mk;
      a_uniq  += uq;                             // uniqueness is unmasked
      float pm = inv_s * mk;

      // overwrite own slice with f16x2 prob-pairs: [cell][9] words
      u32* pw = (u32*)buf + (size_t)(4 * tid + k) * 9;
      pw[0] = pkrtz(e[0] * pm, e[1] * pm);
      pw[1] = pkrtz(e[2] * pm, e[3] * pm);
      pw[2] = pkrtz(e[4] * pm, e[5] * pm);
      pw[3] = pkrtz(e[6] * pm, e[7] * pm);
      pw[4] = pkrtz(e[8] * pm, 0.f);
    }
  }
  __syncthreads();

  // ---- phase C: spread over ALL 4 waves; 15 lanes each = (3 puzzles x 5 pairs) ----
  const int wv = tid >> 6, lane = tid & 63;
  if (lane < 15) {
    const int pz = wv * 3 + lane / 5;            // 0..11
    const int pr = lane % 5;
    if ((long)g * PB + pz < B) {
      const u32* cb = (const u32*)buf;
      h2 hz; hz[0] = (__fp16)0.f; hz[1] = (__fp16)0.f;
      h2 rs[9], cs[9], bs[9];
#pragma unroll
      for (int u = 0; u < 9; ++u) { rs[u] = hz; cs[u] = hz; bs[u] = hz; }
      const int base = pz * 729 + pr;            // word (pz*81+j)*9 + pr
#pragma unroll
      for (int j = 0; j < 81; ++j) {
        h2 v = __builtin_bit_cast(h2, cb[base + 9 * j]);
        rs[j / 9]                    += v;
        cs[j % 9]                    += v;
        bs[(j / 27) * 3 + (j % 9) / 3] += v;
      }
      const float hiw = (pr == 4) ? 0.f : 1.f;   // pad class excluded
      float sq = 0.f;
#pragma unroll
      for (int u = 0; u < 9; ++u) {
        float x;
        x = (float)rs[u][0] - 1.f; sq = fmaf(x, x, sq);
        x = (float)cs[u][0] - 1.f; sq = fmaf(x, x, sq);
        x = (float)bs[u][0] - 1.f; sq = fmaf(x, x, sq);
        x = (float)rs[u][1] - 1.f; sq = fmaf(hiw * x, x, sq);
        x = (float)cs[u][1] - 1.f; sq = fmaf(hiw * x, x, sq);
        x = (float)bs[u][1] - 1.f; sq = fmaf(hiw * x, x, sq);
      }
      a_sq += sq;
    }
  }

  // ---- wave + block reduction, transposed partial store (no atomics) ----
#pragma unroll
  for (int off = 32; off > 0; off >>= 1) {
    a_focal += __shfl_down(a_focal, off);
    a_ent   += __shfl_down(a_ent,   off);
    a_msk   += __shfl_down(a_msk,   off);
    a_uniq  += __shfl_down(a_uniq,  off);
    a_sq    += __shfl_down(a_sq,    off);
  }
  if (lane == 0) {
    sred[wv][0] = a_focal; sred[wv][1] = a_ent; sred[wv][2] = a_msk;
    sred[wv][3] = a_uniq;  sred[wv][4] = a_sq;
  }
  __syncthreads();
  if (tid < 5) {
    float v = sred[0][tid] + sred[1][tid] + sred[2][tid] + sred[3][tid];
    partial[(size_t)tid * ngrid + g] = v;
  }
}

__global__ __launch_bounds__(1024) void sudoku_finalize(
    const float* __restrict__ partial, float* __restrict__ out,
    int ngrid, float invBG)
{
  __shared__ float sb[16][5];
  const int tid = threadIdx.x;
  float s[5] = {0.f, 0.f, 0.f, 0.f, 0.f};
  for (int b = tid; b < ngrid; b += 1024) {
#pragma unroll
    for (int u = 0; u < 5; ++u) s[u] += partial[(size_t)u * ngrid + b];   // coalesced
  }
#pragma unroll
  for (int off = 32; off > 0; off >>= 1)
#pragma unroll
    for (int u = 0; u < 5; ++u) s[u] += __shfl_down(s[u], off);
  const int wv = tid >> 6, lane = tid & 63;
  if (lane == 0) {
#pragma unroll
    for (int u = 0; u < 5; ++u) sb[wv][u] = s[u];
  }
  __syncthreads();
  if (tid == 0) {
    float focal = 0.f, ent = 0.f, msum = 0.f, uniq = 0.f, sq = 0.f;
#pragma unroll
    for (int w = 0; w < 16; ++w) {
      focal += sb[w][0]; ent += sb[w][1]; msum += sb[w][2];
      uniq  += sb[w][3]; sq  += sb[w][4];
    }
    float inv_m = 1.f / (msum + 1e-8f);
    float ce    = focal * inv_m;
    float entl  = 0.1f * ent * inv_m;
    float uql   = 0.1f * uniq * invBG;
    float rcb   = sq * invBG;        // row+col+box means share denominator B*81
    float constraint = (rcb + entl + uql) * 0.2f;
    out[0] = ce + 0.5f * constraint;
  }
}

extern "C" void kernel_launch(void* const* d_in, const int* in_sizes, int n_in,
                              void* d_out, int out_size, void* d_ws, size_t ws_size,
                              hipStream_t stream)
{
  (void)n_in; (void)out_size; (void)ws_size;
  const float* logits  = (const float*)d_in[0];
  const int*   targets = (const int*)d_in[1];
  const int*   puzzles = (const int*)d_in[2];
  float* out = (float*)d_out;
  float* partial = (float*)d_ws;

  const int B = in_sizes[0] / 729;               // B*9*9*9 logits
  const long totalCells = (long)B * 81;
  const int ngrid = (int)((totalCells + CELLS_PB - 1) / CELLS_PB);   // 5462

  sudoku_main<<<ngrid, THREADS, 0, stream>>>(logits, targets, puzzles, partial, B, ngrid);

  const float invBG = 1.f / ((float)B * 81.f);
  sudoku_finalize<<<1, 1024, 0, stream>>>(partial, out, ngrid, invBG);
}